// Round 4
// baseline (983.767 us; speedup 1.0000x reference)
//
#include <hip/hip_runtime.h>
#include <cstddef>
#include <cstdint>

#define NN 50000
#define EE 800000

constexpr float BN_EPS   = 1e-5f;
constexpr float NEGSLOPE = 0.2f;

typedef short s16x8 __attribute__((ext_vector_type(8)));
typedef float f32x4 __attribute__((ext_vector_type(4)));
typedef unsigned short u16x4 __attribute__((ext_vector_type(4)));

__device__ __forceinline__ unsigned short f2bf(float f) {
  unsigned int u = __float_as_uint(f);
  unsigned int r = (u + 0x7fffu + ((u >> 16) & 1u)) >> 16;
  return (unsigned short)r;
}
__device__ __forceinline__ float bf2f(unsigned short u) {
  return __uint_as_float(((unsigned int)u) << 16);
}
__device__ __forceinline__ float leaky(float e) { return e >= 0.f ? e : NEGSLOPE * e; }
__device__ __forceinline__ float sel4(float v0, float v1, float v2, float v3, int h) {
  float r = v0;
  r = (h == 1) ? v1 : r;
  r = (h == 2) ? v2 : r;
  r = (h == 3) ? v3 : r;
  return r;
}
__device__ __forceinline__ void gl_lds16(const unsigned short* g, unsigned short* l) {
  __builtin_amdgcn_global_load_lds(
      (const __attribute__((address_space(1))) unsigned int*)(g),
      (__attribute__((address_space(3))) unsigned int*)(l), 16, 0, 0);
}

// ---------------- CSR build: group edges by (dst*4 + class) ----------------
__global__ void count_edges_k(const int* __restrict__ ei, const int* __restrict__ cls,
                              int* __restrict__ counts) {
  int e = blockIdx.x * 256 + threadIdx.x;
  if (e >= EE) return;
  int dst = ei[EE + e];
  int c   = cls[e];
  atomicAdd(&counts[dst * 4 + c], 1);
}

__global__ void scan_local_k(const int* __restrict__ counts, int* __restrict__ rs,
                             int* __restrict__ bsum, int n) {
  __shared__ int sh[256];
  int b = blockIdx.x, t = threadIdx.x;
  int base = b * 1024;
  int v[4];
  #pragma unroll
  for (int q = 0; q < 4; q++) {
    int i = base + t * 4 + q;
    v[q] = (i < n) ? counts[i] : 0;
  }
  v[1] += v[0]; v[2] += v[1]; v[3] += v[2];
  sh[t] = v[3];
  __syncthreads();
  for (int off = 1; off < 256; off <<= 1) {
    int x = (t >= off) ? sh[t - off] : 0;
    __syncthreads();
    sh[t] += x;
    __syncthreads();
  }
  int prev = (t > 0) ? sh[t - 1] : 0;
  #pragma unroll
  for (int q = 0; q < 4; q++) {
    int i = base + t * 4 + q;
    if (i < n) rs[i + 1] = prev + v[q];
  }
  if (t == 255) bsum[b] = sh[255];
}

__global__ void scan_bsum_k(int* __restrict__ bsum, int nb) {
  __shared__ int sh[256];
  int t = threadIdx.x;
  sh[t] = (t < nb) ? bsum[t] : 0;
  __syncthreads();
  for (int off = 1; off < 256; off <<= 1) {
    int x = (t >= off) ? sh[t - off] : 0;
    __syncthreads();
    sh[t] += x;
    __syncthreads();
  }
  if (t < nb) bsum[t] = (t > 0) ? sh[t - 1] : 0;
}

__global__ void scan_add_k(int* __restrict__ rs, const int* __restrict__ bsum, int n) {
  int b = blockIdx.x, t = threadIdx.x;
  int off = bsum[b];
  #pragma unroll
  for (int q = 0; q < 4; q++) {
    int i = b * 1024 + t * 4 + q;
    if (i < n) rs[i + 1] += off;
  }
  if (b == 0 && t == 0) rs[0] = 0;
}

__global__ void fill_edges_k(const int* __restrict__ ei, const int* __restrict__ cls,
                             const int* __restrict__ rs, int* __restrict__ cursor,
                             int* __restrict__ ssrc) {
  int e = blockIdx.x * 256 + threadIdx.x;
  if (e >= EE) return;
  int dst = ei[EE + e];
  int c   = cls[e];
  int bin = dst * 4 + c;
  int pos = rs[bin] + atomicAdd(&cursor[bin], 1);
  ssrc[pos] = ei[e];
}

// ---------------- BatchNorm (vectorized; optional fused ReLU on read) --------
template <bool RELU>
__global__ void bn_stats_k(const float* __restrict__ x, float* __restrict__ sums,
                           int din, int total4) {
  __shared__ float ls[512];
  int t = threadIdx.x;
  for (int i = t; i < 2 * din; i += 256) ls[i] = 0.f;
  __syncthreads();
  int dmask = din - 1;
  for (int idx = blockIdx.x * 256 + t; idx < total4; idx += gridDim.x * 256) {
    float4 v = ((const float4*)x)[idx];
    int c0 = (idx * 4) & dmask;
    float a0 = RELU ? fmaxf(v.x, 0.f) : v.x;
    float a1 = RELU ? fmaxf(v.y, 0.f) : v.y;
    float a2 = RELU ? fmaxf(v.z, 0.f) : v.z;
    float a3 = RELU ? fmaxf(v.w, 0.f) : v.w;
    atomicAdd(&ls[c0 + 0], a0);
    atomicAdd(&ls[c0 + 1], a1);
    atomicAdd(&ls[c0 + 2], a2);
    atomicAdd(&ls[c0 + 3], a3);
    atomicAdd(&ls[din + c0 + 0], a0 * a0);
    atomicAdd(&ls[din + c0 + 1], a1 * a1);
    atomicAdd(&ls[din + c0 + 2], a2 * a2);
    atomicAdd(&ls[din + c0 + 3], a3 * a3);
  }
  __syncthreads();
  for (int i = t; i < 2 * din; i += 256) atomicAdd(&sums[i], ls[i]);
}

__global__ void bn_finalize_k(const float* __restrict__ sums, const float* __restrict__ g,
                              const float* __restrict__ b, float* __restrict__ scale,
                              float* __restrict__ shift, int din,
                              const float* __restrict__ skb, const float* __restrict__ cb,
                              float* __restrict__ skbe, int hd) {
  int i = threadIdx.x;
  if (i < din) {
    float m  = sums[i] / (float)NN;
    float v  = sums[din + i] / (float)NN - m * m;
    float r  = rsqrtf(v + BN_EPS);
    float sc = r * g[i];
    scale[i] = sc;
    shift[i] = b[i] - m * sc;
  }
  if (i < hd) {
    float acc = skb[i];
    #pragma unroll
    for (int j = 0; j < 4; j++) acc += cb[j * hd + i];
    skbe[i] = acc;
  }
}

template <bool RELU>
__global__ void bn_apply_bf16_k(const float* __restrict__ x, unsigned short* __restrict__ xn,
                                const float* __restrict__ scale, const float* __restrict__ shift,
                                int dmask, int total4) {
  for (int i = blockIdx.x * 256 + threadIdx.x; i < total4; i += gridDim.x * 256) {
    float4 v = ((const float4*)x)[i];
    int c0 = (i * 4) & dmask;
    if (RELU) {
      v.x = fmaxf(v.x, 0.f); v.y = fmaxf(v.y, 0.f);
      v.z = fmaxf(v.z, 0.f); v.w = fmaxf(v.w, 0.f);
    }
    u16x4 o;
    o[0] = f2bf(v.x * scale[c0 + 0] + shift[c0 + 0]);
    o[1] = f2bf(v.y * scale[c0 + 1] + shift[c0 + 1]);
    o[2] = f2bf(v.z * scale[c0 + 2] + shift[c0 + 2]);
    o[3] = f2bf(v.w * scale[c0 + 3] + shift[c0 + 3]);
    ((u16x4*)xn)[i] = o;
  }
}

// ---------------- weight convert+transpose to bf16 (layers 0/1) ----------------
__global__ void conv_weights_k(const float* __restrict__ skW0, const float* __restrict__ W0,
                               const float* __restrict__ skW1, const float* __restrict__ W1,
                               unsigned short* __restrict__ wt) {
  int o = blockIdx.x * 256 + threadIdx.x;
  if (o >= 409600) return;
  float v;
  if (o < 16384) {                       // skW0^T [256][64]
    int n = o >> 6, k = o & 63;
    v = skW0[k * 256 + n];
  } else if (o < 81920) {                // W0^T [4][256][64]
    int w = o - 16384; int j = w >> 14; w &= 16383;
    int n = w >> 6, k = w & 63;
    v = W0[j * 16384 + k * 256 + n];
  } else if (o < 147456) {               // skW1^T [256][256]
    int w = o - 81920;
    int n = w >> 8, k = w & 255;
    v = skW1[k * 256 + n];
  } else {                               // W1^T [4][256][256]
    int w = o - 147456; int j = w >> 16; w &= 65535;
    int n = w >> 8, k = w & 255;
    v = W1[j * 65536 + k * 256 + n];
  }
  wt[o] = f2bf(v);
}

// ---------------- bf16 MFMA GEMM (batched over z) with fused attn scores ----
// Each wave's 64-col span == one head, so es/ed for (row, head) reduce
// entirely within the wave (16-lane butterfly over lm).
__global__ __launch_bounds__(256) void gemm_bf16_k(
    const unsigned short* __restrict__ A,   // [M,K] bf16
    const unsigned short* __restrict__ Bt,  // [z][N,K] bf16
    const float* __restrict__ bias,         // [N] or null (skip path)
    float* __restrict__ Cf,                 // f32 out (skip path, or null)
    unsigned short* __restrict__ Cb,        // bf16 out (conv path, or null)
    const float* __restrict__ asrc,         // [4][256] or null
    const float* __restrict__ adst,         // [4][256] or null
    float* __restrict__ es4,                // [4][NN][4] or null
    float* __restrict__ ed4,                // [4][NN][4] or null
    int M, int K, int N, int strideBt, long long strideC) {
  __shared__ unsigned short As[128 * 32];
  __shared__ unsigned short Bs[128 * 32];
  int z = blockIdx.z;
  Bt += (size_t)z * strideBt;
  int tid  = threadIdx.x;
  int lane = tid & 63;
  int w    = tid >> 6;
  int lm = lane & 15, lq = lane >> 4;
  int row0 = blockIdx.y * 128, col0 = blockIdx.x * 128;
  int wr = (w >> 1) * 64, wc = (w & 1) * 64;
  f32x4 acc[4][4];
  #pragma unroll
  for (int i = 0; i < 4; i++)
    #pragma unroll
    for (int j = 0; j < 4; j++) acc[i][j] = {0.f, 0.f, 0.f, 0.f};
  int ldsbase = (tid & ~63) * 16;

  for (int k0 = 0; k0 < K; k0 += 32) {
    #pragma unroll
    for (int r = 0; r < 2; r++) {
      int ia = r * 256 + tid;
      int arow = row0 + (ia >> 2);
      if (arow >= M) arow = M - 1;
      const unsigned short* ga = A + (size_t)arow * K + k0 + (ia & 3) * 8;
      gl_lds16(ga, (unsigned short*)((char*)As + r * 4096 + ldsbase));
      int bcol = col0 + (ia >> 2);
      const unsigned short* gb = Bt + (size_t)bcol * K + k0 + (ia & 3) * 8;
      gl_lds16(gb, (unsigned short*)((char*)Bs + r * 4096 + ldsbase));
    }
    __syncthreads();
    s16x8 af[4], bfr[4];
    #pragma unroll
    for (int i = 0; i < 4; i++)
      af[i] = *(const s16x8*)&As[(wr + i * 16 + lm) * 32 + lq * 8];
    #pragma unroll
    for (int j = 0; j < 4; j++)
      bfr[j] = *(const s16x8*)&Bs[(wc + j * 16 + lm) * 32 + lq * 8];
    #pragma unroll
    for (int i = 0; i < 4; i++)
      #pragma unroll
      for (int j = 0; j < 4; j++)
        acc[i][j] = __builtin_amdgcn_mfma_f32_16x16x32_bf16(af[i], bfr[j], acc[i][j], 0, 0, 0);
    __syncthreads();
  }

  // store C
  #pragma unroll
  for (int i = 0; i < 4; i++) {
    #pragma unroll
    for (int j = 0; j < 4; j++) {
      int c = col0 + wc + j * 16 + lm;
      #pragma unroll
      for (int rg = 0; rg < 4; rg++) {
        int r = row0 + wr + i * 16 + lq * 4 + rg;
        if (r < M) {
          float v = acc[i][j][rg];
          if (Cf) {
            if (bias) v += bias[c];
            Cf[(size_t)r * N + c] = v;
          } else {
            Cb[(size_t)z * strideC + (size_t)r * N + c] = f2bf(v);
          }
        }
      }
    }
  }

  // fused attention scores (conv path only)
  if (es4) {
    int hh = (col0 + wc) >> 6;
    float as_v[4], ad_v[4];
    #pragma unroll
    for (int j = 0; j < 4; j++) {
      int gcol = col0 + wc + j * 16 + lm;
      as_v[j] = asrc[z * 256 + gcol];
      ad_v[j] = adst[z * 256 + gcol];
    }
    #pragma unroll
    for (int i = 0; i < 4; i++) {
      #pragma unroll
      for (int rg = 0; rg < 4; rg++) {
        float se = 0.f, sd = 0.f;
        #pragma unroll
        for (int j = 0; j < 4; j++) {
          se += acc[i][j][rg] * as_v[j];
          sd += acc[i][j][rg] * ad_v[j];
        }
        #pragma unroll
        for (int off = 8; off > 0; off >>= 1) {
          se += __shfl_xor(se, off);
          sd += __shfl_xor(sd, off);
        }
        int r = row0 + wr + i * 16 + lq * 4 + rg;
        if (r < M) {
          if (lm == 0) es4[((size_t)z * NN + r) * 4 + hh] = se;
          if (lm == 1) ed4[((size_t)z * NN + r) * 4 + hh] = sd;
        }
      }
    }
  }
}

// ---------------- fused aggregate: all 4 classes, single pass, one wave/node ----
__global__ __launch_bounds__(256) void gat_agg4_fused_k(
    const unsigned short* __restrict__ hfeat4,  // [4][NN][256] bf16
    const float* __restrict__ es4,              // [4][NN][4]
    const float* __restrict__ ed4,              // [4][NN][4]
    const int* __restrict__ rs, const int* __restrict__ ssrc,
    float* __restrict__ x0) {                   // [NN][256] += msg
  int node = blockIdx.x * 4 + (threadIdx.x >> 6);
  int lane = threadIdx.x & 63;
  if (node >= NN) return;
  int r0 = rs[node * 4 + 0], r1 = rs[node * 4 + 1], r2 = rs[node * 4 + 2],
      r3 = rs[node * 4 + 3], r4 = rs[node * 4 + 4];
  if (r0 == r4) return;
  int h = lane >> 4;

  float acc[4][4];
  float den[4];
  #pragma unroll
  for (int j = 0; j < 4; j++) {
    den[j] = 0.f;
    #pragma unroll
    for (int q = 0; q < 4; q++) acc[j][q] = 0.f;
  }

  #pragma unroll
  for (int j = 0; j < 4; j++) {
    int beg = (j == 0) ? r0 : (j == 1) ? r1 : (j == 2) ? r2 : r3;
    int end = (j == 0) ? r1 : (j == 1) ? r2 : (j == 2) ? r3 : r4;
    if (beg == end) continue;
    const float4 edv = *(const float4*)(ed4 + ((size_t)j * NN + node) * 4);
    const unsigned short* hfj = hfeat4 + (size_t)j * NN * 256;
    const float* esj = es4 + (size_t)j * NN * 4;
    for (int base = beg; base < end; base += 64) {
      int idx = base + lane;
      int s = -1;
      float w0 = 0.f, w1 = 0.f, w2 = 0.f, w3 = 0.f;
      if (idx < end) {
        s = ssrc[idx];
        float4 ev = *(const float4*)(esj + (size_t)s * 4);
        w0 = __expf(leaky(ev.x + edv.x));
        w1 = __expf(leaky(ev.y + edv.y));
        w2 = __expf(leaky(ev.z + edv.z));
        w3 = __expf(leaky(ev.w + edv.w));
      }
      int n_e = min(64, end - base);
      #pragma unroll 2
      for (int i = 0; i < n_e; i++) {
        int si   = __shfl(s, i);
        float b0 = __shfl(w0, i), b1 = __shfl(w1, i),
              b2 = __shfl(w2, i), b3 = __shfl(w3, i);
        float wh = sel4(b0, b1, b2, b3, h);
        u16x4 f = *(const u16x4*)(hfj + (size_t)si * 256 + lane * 4);
        acc[j][0] += wh * bf2f(f[0]);
        acc[j][1] += wh * bf2f(f[1]);
        acc[j][2] += wh * bf2f(f[2]);
        acc[j][3] += wh * bf2f(f[3]);
        den[j] += wh;
      }
    }
  }

  float4* xp = (float4*)(x0 + (size_t)node * 256 + lane * 4);
  float4 cur = *xp;
  #pragma unroll
  for (int j = 0; j < 4; j++) {
    if (den[j] > 0.f) {
      float inv = 1.f / den[j];
      cur.x += acc[j][0] * inv;
      cur.y += acc[j][1] * inv;
      cur.z += acc[j][2] * inv;
      cur.w += acc[j][3] * inv;
    }
  }
  *xp = cur;
}

// ---------------- layer 2 fused: 5 skinny GEMMs + scores ----------------
__global__ __launch_bounds__(256) void layer2_fused_k(
    const unsigned short* __restrict__ xa,  // [NN][256] bf16
    const float* __restrict__ skW,          // [256][2]
    const float* __restrict__ W,            // [4][256][2]
    const float* __restrict__ As2,          // [4][2]
    const float* __restrict__ Ad2,          // [4][2]
    const float* __restrict__ skbe,         // [2]
    float* __restrict__ x02,                // [NN][2]
    float* __restrict__ hf2,                // [4][NN][2]
    float* __restrict__ es2,                // [4][NN]
    float* __restrict__ ed2) {              // [4][NN]
  __shared__ float wsk[256][2];
  __shared__ float wcl[4][256][2];
  int t = threadIdx.x;
  wsk[t][0] = skW[t * 2];
  wsk[t][1] = skW[t * 2 + 1];
  #pragma unroll
  for (int j = 0; j < 4; j++) {
    wcl[j][t][0] = W[j * 512 + t * 2];
    wcl[j][t][1] = W[j * 512 + t * 2 + 1];
  }
  __syncthreads();
  int node = blockIdx.x * 256 + t;
  if (node >= NN) return;
  const unsigned short* row = xa + (size_t)node * 256;
  float s0 = 0.f, s1 = 0.f;
  float h[4][2] = {};
  for (int k = 0; k < 256; k += 4) {
    u16x4 xr = *(const u16x4*)(row + k);
    #pragma unroll
    for (int q = 0; q < 4; q++) {
      float xv = bf2f(xr[q]);
      s0 += xv * wsk[k + q][0];
      s1 += xv * wsk[k + q][1];
      #pragma unroll
      for (int j = 0; j < 4; j++) {
        h[j][0] += xv * wcl[j][k + q][0];
        h[j][1] += xv * wcl[j][k + q][1];
      }
    }
  }
  x02[(size_t)node * 2]     = s0 + skbe[0];
  x02[(size_t)node * 2 + 1] = s1 + skbe[1];
  #pragma unroll
  for (int j = 0; j < 4; j++) {
    hf2[((size_t)j * NN + node) * 2]     = h[j][0];
    hf2[((size_t)j * NN + node) * 2 + 1] = h[j][1];
    es2[(size_t)j * NN + node] = h[j][0] * As2[j * 2] + h[j][1] * As2[j * 2 + 1];
    ed2[(size_t)j * NN + node] = h[j][0] * Ad2[j * 2] + h[j][1] * Ad2[j * 2 + 1];
  }
}

// ---------------- fused aggregate for layer 2 (H=1, D=2) ----------------
__global__ __launch_bounds__(256) void gat_agg2_fused_k(
    const float* __restrict__ hf2,  // [4][NN][2]
    const float* __restrict__ es2,  // [4][NN]
    const float* __restrict__ ed2,  // [4][NN]
    const int* __restrict__ rs, const int* __restrict__ ssrc,
    float* __restrict__ x0) {       // [NN][2]
  int node = blockIdx.x * 4 + (threadIdx.x >> 6);
  int lane = threadIdx.x & 63;
  if (node >= NN) return;
  float add0 = 0.f, add1 = 0.f;
  #pragma unroll
  for (int j = 0; j < 4; j++) {
    int beg = rs[node * 4 + j], end = rs[node * 4 + j + 1];
    if (beg == end) continue;
    float edv = ed2[(size_t)j * NN + node];
    float nw = 0.f, n0 = 0.f, n1 = 0.f;
    for (int idx = beg + lane; idx < end; idx += 64) {
      int s = ssrc[idx];
      float w = __expf(leaky(es2[(size_t)j * NN + s] + edv));
      float2 f = *(const float2*)(hf2 + ((size_t)j * NN + s) * 2);
      nw += w; n0 += w * f.x; n1 += w * f.y;
    }
    #pragma unroll
    for (int off = 32; off > 0; off >>= 1) {
      nw += __shfl_xor(nw, off);
      n0 += __shfl_xor(n0, off);
      n1 += __shfl_xor(n1, off);
    }
    float inv = 1.f / nw;
    add0 += n0 * inv;
    add1 += n1 * inv;
  }
  if (lane == 0) {
    x0[(size_t)node * 2]     += add0;
    x0[(size_t)node * 2 + 1] += add1;
  }
}

__global__ void relu_k(const float* __restrict__ in, float* __restrict__ out, int n) {
  for (int i = blockIdx.x * 256 + threadIdx.x; i < n; i += gridDim.x * 256)
    out[i] = fmaxf(in[i], 0.f);
}

// ---------------- launch ----------------
extern "C" void kernel_launch(void* const* d_in, const int* in_sizes, int n_in,
                              void* d_out, int out_size, void* d_ws, size_t ws_size,
                              hipStream_t stream) {
  (void)in_sizes; (void)n_in; (void)out_size; (void)ws_size;
  const float* x_in = (const float*)d_in[0];
  const int* ei  = (const int*)d_in[1];
  const int* cls = (const int*)d_in[2];
  const float *W[3], *Asr[3], *Adr[3], *cb[3], *skW[3], *skb[3], *bng[3], *bnb[3];
  for (int i = 0; i < 3; i++) {
    int b = 3 + 8 * i;
    W[i]   = (const float*)d_in[b + 0];
    Asr[i] = (const float*)d_in[b + 1];
    Adr[i] = (const float*)d_in[b + 2];
    cb[i]  = (const float*)d_in[b + 3];
    skW[i] = (const float*)d_in[b + 4];
    skb[i] = (const float*)d_in[b + 5];
    bng[i] = (const float*)d_in[b + 6];
    bnb[i] = (const float*)d_in[b + 7];
  }
  float* out = (float*)d_out;

  char* wsp = (char*)d_ws;
  auto alloc = [&](size_t bytes) {
    char* p = wsp;
    wsp += (bytes + 255) & ~(size_t)255;
    return p;
  };
  float*          x0     = (float*)alloc((size_t)NN * 256 * 4);
  unsigned short* xa     = (unsigned short*)alloc((size_t)NN * 256 * 2);
  unsigned short* hfeat4 = (unsigned short*)alloc((size_t)4 * NN * 256 * 2);
  float*          hf2    = (float*)alloc((size_t)4 * NN * 2 * 4);
  float*          es4    = (float*)alloc((size_t)4 * NN * 4 * 4);
  float*          ed4    = (float*)alloc((size_t)4 * NN * 4 * 4);
  float*          stats  = (float*)alloc(512 * 4);
  float*          scale  = (float*)alloc(256 * 4);
  float*          shift  = (float*)alloc(256 * 4);
  float*          skbe   = (float*)alloc(256 * 4);
  unsigned short* wt     = (unsigned short*)alloc((size_t)409600 * 2);
  int*            counts = (int*)alloc((size_t)NN * 4 * 4);
  int*            rs     = (int*)alloc(((size_t)NN * 4 + 1) * 4);
  int*            cursor = (int*)alloc((size_t)NN * 4 * 4);
  int*            bsum   = (int*)alloc(256 * 4);
  int*            ssrc   = (int*)alloc((size_t)EE * 4);

  // ---- CSR by (dst, class) ----
  hipMemsetAsync(counts, 0, (size_t)NN * 4 * 4, stream);
  hipMemsetAsync(cursor, 0, (size_t)NN * 4 * 4, stream);
  count_edges_k<<<(EE + 255) / 256, 256, 0, stream>>>(ei, cls, counts);
  scan_local_k<<<196, 256, 0, stream>>>(counts, rs, bsum, NN * 4);
  scan_bsum_k<<<1, 256, 0, stream>>>(bsum, 196);
  scan_add_k<<<196, 256, 0, stream>>>(rs, bsum, NN * 4);
  fill_edges_k<<<(EE + 255) / 256, 256, 0, stream>>>(ei, cls, rs, cursor, ssrc);

  // ---- weights -> bf16 transposed (layers 0/1) ----
  conv_weights_k<<<1600, 256, 0, stream>>>(skW[0], W[0], skW[1], W[1], wt);

  // ---- layers 0 and 1 ----
  for (int L = 0; L < 2; L++) {
    int din = (L == 0) ? 64 : 256;
    int total4 = NN * din / 4;
    const float* lin = (L == 0) ? x_in : x0;
    hipMemsetAsync(stats, 0, 512 * 4, stream);
    if (L == 0) {
      bn_stats_k<false><<<512, 256, 0, stream>>>(lin, stats, din, total4);
    } else {
      bn_stats_k<true><<<512, 256, 0, stream>>>(lin, stats, din, total4);
    }
    bn_finalize_k<<<1, 256, 0, stream>>>(stats, bng[L], bnb[L], scale, shift, din,
                                         skb[L], cb[L], skbe, 256);
    if (L == 0) {
      bn_apply_bf16_k<false><<<1024, 256, 0, stream>>>(lin, xa, scale, shift, din - 1, total4);
    } else {
      bn_apply_bf16_k<true><<<1024, 256, 0, stream>>>(lin, xa, scale, shift, din - 1, total4);
    }

    const unsigned short* wsk = wt + (L ? 81920 : 0);
    dim3 ggs(2, (NN + 127) / 128, 1);
    gemm_bf16_k<<<ggs, 256, 0, stream>>>(xa, wsk, skbe, x0, nullptr,
                                         nullptr, nullptr, nullptr, nullptr,
                                         NN, din, 256, 0, 0);
    const unsigned short* wcv = wt + (L ? 147456 : 16384);
    int sB = L ? 65536 : 16384;
    dim3 ggc(2, (NN + 127) / 128, 4);
    gemm_bf16_k<<<ggc, 256, 0, stream>>>(xa, wcv, nullptr, nullptr, hfeat4,
                                         Asr[L], Adr[L], es4, ed4,
                                         NN, din, 256, sB, (long long)NN * 256);
    gat_agg4_fused_k<<<(NN + 3) / 4, 256, 0, stream>>>(hfeat4, es4, ed4, rs, ssrc, x0);
  }

  // ---- layer 2 ----
  hipMemsetAsync(stats, 0, 512 * 4, stream);
  bn_stats_k<true><<<512, 256, 0, stream>>>(x0, stats, 256, NN * 64);
  bn_finalize_k<<<1, 256, 0, stream>>>(stats, bng[2], bnb[2], scale, shift, 256,
                                       skb[2], cb[2], skbe, 2);
  bn_apply_bf16_k<true><<<1024, 256, 0, stream>>>(x0, xa, scale, shift, 255, NN * 64);
  layer2_fused_k<<<(NN + 255) / 256, 256, 0, stream>>>(xa, skW[2], W[2], Asr[2], Adr[2],
                                                       skbe, x0, hf2, es4, ed4);
  gat_agg2_fused_k<<<(NN + 3) / 4, 256, 0, stream>>>(hf2, es4, ed4, rs, ssrc, x0);
  relu_k<<<64, 256, 0, stream>>>(x0, out, NN * 2);
}

// Round 5
// 758.885 us; speedup vs baseline: 1.2963x; 1.2963x over previous
//
#include <hip/hip_runtime.h>
#include <cstddef>
#include <cstdint>

#define NN 50000
#define EE 800000

constexpr float BN_EPS   = 1e-5f;
constexpr float NEGSLOPE = 0.2f;

typedef short s16x8 __attribute__((ext_vector_type(8)));
typedef float f32x4 __attribute__((ext_vector_type(4)));
typedef unsigned short u16x4 __attribute__((ext_vector_type(4)));

__device__ __forceinline__ unsigned short f2bf(float f) {
  unsigned int u = __float_as_uint(f);
  unsigned int r = (u + 0x7fffu + ((u >> 16) & 1u)) >> 16;
  return (unsigned short)r;
}
__device__ __forceinline__ float bf2f(unsigned short u) {
  return __uint_as_float(((unsigned int)u) << 16);
}
__device__ __forceinline__ float leaky(float e) { return e >= 0.f ? e : NEGSLOPE * e; }
__device__ __forceinline__ float sel4(float v0, float v1, float v2, float v3, int h) {
  float r = v0;
  r = (h == 1) ? v1 : r;
  r = (h == 2) ? v2 : r;
  r = (h == 3) ? v3 : r;
  return r;
}
__device__ __forceinline__ void gl_lds16(const unsigned short* g, unsigned short* l) {
  __builtin_amdgcn_global_load_lds(
      (const __attribute__((address_space(1))) unsigned int*)(g),
      (__attribute__((address_space(3))) unsigned int*)(l), 16, 0, 0);
}

// ---------------- CSR build: group edges by (dst*4 + class) ----------------
__global__ void count_edges_k(const int* __restrict__ ei, const int* __restrict__ cls,
                              int* __restrict__ counts) {
  int e = blockIdx.x * 256 + threadIdx.x;
  if (e >= EE) return;
  int dst = ei[EE + e];
  int c   = cls[e];
  atomicAdd(&counts[dst * 4 + c], 1);
}

__global__ void scan_local_k(const int* __restrict__ counts, int* __restrict__ rs,
                             int* __restrict__ bsum, int n) {
  __shared__ int sh[256];
  int b = blockIdx.x, t = threadIdx.x;
  int base = b * 1024;
  int v[4];
  #pragma unroll
  for (int q = 0; q < 4; q++) {
    int i = base + t * 4 + q;
    v[q] = (i < n) ? counts[i] : 0;
  }
  v[1] += v[0]; v[2] += v[1]; v[3] += v[2];
  sh[t] = v[3];
  __syncthreads();
  for (int off = 1; off < 256; off <<= 1) {
    int x = (t >= off) ? sh[t - off] : 0;
    __syncthreads();
    sh[t] += x;
    __syncthreads();
  }
  int prev = (t > 0) ? sh[t - 1] : 0;
  #pragma unroll
  for (int q = 0; q < 4; q++) {
    int i = base + t * 4 + q;
    if (i < n) rs[i + 1] = prev + v[q];
  }
  if (t == 255) bsum[b] = sh[255];
}

__global__ void scan_bsum_k(int* __restrict__ bsum, int nb) {
  __shared__ int sh[256];
  int t = threadIdx.x;
  sh[t] = (t < nb) ? bsum[t] : 0;
  __syncthreads();
  for (int off = 1; off < 256; off <<= 1) {
    int x = (t >= off) ? sh[t - off] : 0;
    __syncthreads();
    sh[t] += x;
    __syncthreads();
  }
  if (t < nb) bsum[t] = (t > 0) ? sh[t - 1] : 0;
}

__global__ void scan_add_k(int* __restrict__ rs, const int* __restrict__ bsum, int n) {
  int b = blockIdx.x, t = threadIdx.x;
  int off = bsum[b];
  #pragma unroll
  for (int q = 0; q < 4; q++) {
    int i = b * 1024 + t * 4 + q;
    if (i < n) rs[i + 1] += off;
  }
  if (b == 0 && t == 0) rs[0] = 0;
}

__global__ void fill_edges_k(const int* __restrict__ ei, const int* __restrict__ cls,
                             const int* __restrict__ rs, int* __restrict__ cursor,
                             int* __restrict__ ssrc) {
  int e = blockIdx.x * 256 + threadIdx.x;
  if (e >= EE) return;
  int dst = ei[EE + e];
  int c   = cls[e];
  int bin = dst * 4 + c;
  int pos = rs[bin] + atomicAdd(&cursor[bin], 1);
  ssrc[pos] = ei[e];
}

// ---------------- BatchNorm (float4 loads, register accumulation) ----------
// Grid-stride in float4 units = gridDim*256*4 elements, a multiple of din,
// so each thread's 4 channels are loop-invariant -> register sums.
template <bool RELU>
__global__ void bn_stats_k(const float* __restrict__ x, float* __restrict__ sums,
                           int din, int total4) {
  __shared__ float ls[512];
  int t = threadIdx.x;
  for (int i = t; i < 2 * din; i += 256) ls[i] = 0.f;
  __syncthreads();
  int dmask = din - 1;
  int start = blockIdx.x * 256 + t;
  int c0 = (start * 4) & dmask;
  float s[4] = {0.f, 0.f, 0.f, 0.f};
  float ss[4] = {0.f, 0.f, 0.f, 0.f};
  for (int idx = start; idx < total4; idx += gridDim.x * 256) {
    float4 v = ((const float4*)x)[idx];
    float a0 = RELU ? fmaxf(v.x, 0.f) : v.x;
    float a1 = RELU ? fmaxf(v.y, 0.f) : v.y;
    float a2 = RELU ? fmaxf(v.z, 0.f) : v.z;
    float a3 = RELU ? fmaxf(v.w, 0.f) : v.w;
    s[0] += a0; s[1] += a1; s[2] += a2; s[3] += a3;
    ss[0] += a0 * a0; ss[1] += a1 * a1; ss[2] += a2 * a2; ss[3] += a3 * a3;
  }
  #pragma unroll
  for (int q = 0; q < 4; q++) {
    atomicAdd(&ls[c0 + q], s[q]);
    atomicAdd(&ls[din + c0 + q], ss[q]);
  }
  __syncthreads();
  for (int i = t; i < 2 * din; i += 256) atomicAdd(&sums[i], ls[i]);
}

__global__ void bn_finalize_k(const float* __restrict__ sums, const float* __restrict__ g,
                              const float* __restrict__ b, float* __restrict__ scale,
                              float* __restrict__ shift, int din,
                              const float* __restrict__ skb, const float* __restrict__ cb,
                              float* __restrict__ skbe, int hd) {
  int i = threadIdx.x;
  if (i < din) {
    float m  = sums[i] / (float)NN;
    float v  = sums[din + i] / (float)NN - m * m;
    float r  = rsqrtf(v + BN_EPS);
    float sc = r * g[i];
    scale[i] = sc;
    shift[i] = b[i] - m * sc;
  }
  if (i < hd) {
    float acc = skb[i];
    #pragma unroll
    for (int j = 0; j < 4; j++) acc += cb[j * hd + i];
    skbe[i] = acc;
  }
}

template <bool RELU>
__global__ void bn_apply_bf16_k(const float* __restrict__ x, unsigned short* __restrict__ xn,
                                const float* __restrict__ scale, const float* __restrict__ shift,
                                int dmask, int total4) {
  for (int i = blockIdx.x * 256 + threadIdx.x; i < total4; i += gridDim.x * 256) {
    float4 v = ((const float4*)x)[i];
    int c0 = (i * 4) & dmask;
    if (RELU) {
      v.x = fmaxf(v.x, 0.f); v.y = fmaxf(v.y, 0.f);
      v.z = fmaxf(v.z, 0.f); v.w = fmaxf(v.w, 0.f);
    }
    u16x4 o;
    o[0] = f2bf(v.x * scale[c0 + 0] + shift[c0 + 0]);
    o[1] = f2bf(v.y * scale[c0 + 1] + shift[c0 + 1]);
    o[2] = f2bf(v.z * scale[c0 + 2] + shift[c0 + 2]);
    o[3] = f2bf(v.w * scale[c0 + 3] + shift[c0 + 3]);
    ((u16x4*)xn)[i] = o;
  }
}

// ---------------- weight convert+transpose to bf16 (layers 0/1) ----------------
__global__ void conv_weights_k(const float* __restrict__ skW0, const float* __restrict__ W0,
                               const float* __restrict__ skW1, const float* __restrict__ W1,
                               unsigned short* __restrict__ wt) {
  int o = blockIdx.x * 256 + threadIdx.x;
  if (o >= 409600) return;
  float v;
  if (o < 16384) {                       // skW0^T [256][64]
    int n = o >> 6, k = o & 63;
    v = skW0[k * 256 + n];
  } else if (o < 81920) {                // W0^T [4][256][64]
    int w = o - 16384; int j = w >> 14; w &= 16383;
    int n = w >> 6, k = w & 63;
    v = W0[j * 16384 + k * 256 + n];
  } else if (o < 147456) {               // skW1^T [256][256]
    int w = o - 81920;
    int n = w >> 8, k = w & 255;
    v = skW1[k * 256 + n];
  } else {                               // W1^T [4][256][256]
    int w = o - 147456; int j = w >> 16; w &= 65535;
    int n = w >> 8, k = w & 255;
    v = W1[j * 65536 + k * 256 + n];
  }
  wt[o] = f2bf(v);
}

// ---------------- bf16 MFMA GEMM (batched over z) with fused attn scores ----
__global__ __launch_bounds__(256) void gemm_bf16_k(
    const unsigned short* __restrict__ A,   // [M,K] bf16
    const unsigned short* __restrict__ Bt,  // [z][N,K] bf16
    const float* __restrict__ bias,         // [N] or null (skip path)
    float* __restrict__ Cf,                 // f32 out (skip path, or null)
    unsigned short* __restrict__ Cb,        // bf16 out (conv path, or null)
    const float* __restrict__ asrc,         // [4][256] or null
    const float* __restrict__ adst,         // [4][256] or null
    float* __restrict__ es4,                // [4][NN][4] or null
    float* __restrict__ ed4,                // [4][NN][4] or null
    int M, int K, int N, int strideBt, long long strideC) {
  __shared__ unsigned short As[128 * 32];
  __shared__ unsigned short Bs[128 * 32];
  int z = blockIdx.z;
  Bt += (size_t)z * strideBt;
  int tid  = threadIdx.x;
  int lane = tid & 63;
  int w    = tid >> 6;
  int lm = lane & 15, lq = lane >> 4;
  int row0 = blockIdx.y * 128, col0 = blockIdx.x * 128;
  int wr = (w >> 1) * 64, wc = (w & 1) * 64;
  f32x4 acc[4][4];
  #pragma unroll
  for (int i = 0; i < 4; i++)
    #pragma unroll
    for (int j = 0; j < 4; j++) acc[i][j] = {0.f, 0.f, 0.f, 0.f};
  int ldsbase = (tid & ~63) * 16;

  for (int k0 = 0; k0 < K; k0 += 32) {
    #pragma unroll
    for (int r = 0; r < 2; r++) {
      int ia = r * 256 + tid;
      int arow = row0 + (ia >> 2);
      if (arow >= M) arow = M - 1;
      const unsigned short* ga = A + (size_t)arow * K + k0 + (ia & 3) * 8;
      gl_lds16(ga, (unsigned short*)((char*)As + r * 4096 + ldsbase));
      int bcol = col0 + (ia >> 2);
      const unsigned short* gb = Bt + (size_t)bcol * K + k0 + (ia & 3) * 8;
      gl_lds16(gb, (unsigned short*)((char*)Bs + r * 4096 + ldsbase));
    }
    __syncthreads();
    s16x8 af[4], bfr[4];
    #pragma unroll
    for (int i = 0; i < 4; i++)
      af[i] = *(const s16x8*)&As[(wr + i * 16 + lm) * 32 + lq * 8];
    #pragma unroll
    for (int j = 0; j < 4; j++)
      bfr[j] = *(const s16x8*)&Bs[(wc + j * 16 + lm) * 32 + lq * 8];
    #pragma unroll
    for (int i = 0; i < 4; i++)
      #pragma unroll
      for (int j = 0; j < 4; j++)
        acc[i][j] = __builtin_amdgcn_mfma_f32_16x16x32_bf16(af[i], bfr[j], acc[i][j], 0, 0, 0);
    __syncthreads();
  }

  // store C
  #pragma unroll
  for (int i = 0; i < 4; i++) {
    #pragma unroll
    for (int j = 0; j < 4; j++) {
      int c = col0 + wc + j * 16 + lm;
      #pragma unroll
      for (int rg = 0; rg < 4; rg++) {
        int r = row0 + wr + i * 16 + lq * 4 + rg;
        if (r < M) {
          float v = acc[i][j][rg];
          if (Cf) {
            if (bias) v += bias[c];
            Cf[(size_t)r * N + c] = v;
          } else {
            Cb[(size_t)z * strideC + (size_t)r * N + c] = f2bf(v);
          }
        }
      }
    }
  }

  // fused attention scores (conv path only)
  if (es4) {
    int hh = (col0 + wc) >> 6;
    float as_v[4], ad_v[4];
    #pragma unroll
    for (int j = 0; j < 4; j++) {
      int gcol = col0 + wc + j * 16 + lm;
      as_v[j] = asrc[z * 256 + gcol];
      ad_v[j] = adst[z * 256 + gcol];
    }
    #pragma unroll
    for (int i = 0; i < 4; i++) {
      #pragma unroll
      for (int rg = 0; rg < 4; rg++) {
        float se = 0.f, sd = 0.f;
        #pragma unroll
        for (int j = 0; j < 4; j++) {
          se += acc[i][j][rg] * as_v[j];
          sd += acc[i][j][rg] * ad_v[j];
        }
        #pragma unroll
        for (int off = 8; off > 0; off >>= 1) {
          se += __shfl_xor(se, off);
          sd += __shfl_xor(sd, off);
        }
        int r = row0 + wr + i * 16 + lq * 4 + rg;
        if (r < M) {
          if (lm == 0) es4[((size_t)z * NN + r) * 4 + hh] = se;
          if (lm == 1) ed4[((size_t)z * NN + r) * 4 + hh] = sd;
        }
      }
    }
  }
}

// ---------------- fused aggregate: all 4 classes, single pass, one wave/node ----
__global__ __launch_bounds__(256) void gat_agg4_fused_k(
    const unsigned short* __restrict__ hfeat4,  // [4][NN][256] bf16
    const float* __restrict__ es4,              // [4][NN][4]
    const float* __restrict__ ed4,              // [4][NN][4]
    const int* __restrict__ rs, const int* __restrict__ ssrc,
    float* __restrict__ x0) {                   // [NN][256] += msg
  int node = blockIdx.x * 4 + (threadIdx.x >> 6);
  int lane = threadIdx.x & 63;
  if (node >= NN) return;
  int r0 = rs[node * 4 + 0], r1 = rs[node * 4 + 1], r2 = rs[node * 4 + 2],
      r3 = rs[node * 4 + 3], r4 = rs[node * 4 + 4];
  if (r0 == r4) return;
  int h = lane >> 4;

  float acc[4][4];
  float den[4];
  #pragma unroll
  for (int j = 0; j < 4; j++) {
    den[j] = 0.f;
    #pragma unroll
    for (int q = 0; q < 4; q++) acc[j][q] = 0.f;
  }

  #pragma unroll
  for (int j = 0; j < 4; j++) {
    int beg = (j == 0) ? r0 : (j == 1) ? r1 : (j == 2) ? r2 : r3;
    int end = (j == 0) ? r1 : (j == 1) ? r2 : (j == 2) ? r3 : r4;
    if (beg == end) continue;
    const float4 edv = *(const float4*)(ed4 + ((size_t)j * NN + node) * 4);
    const unsigned short* hfj = hfeat4 + (size_t)j * NN * 256;
    const float* esj = es4 + (size_t)j * NN * 4;
    for (int base = beg; base < end; base += 64) {
      int idx = base + lane;
      int s = -1;
      float w0 = 0.f, w1 = 0.f, w2 = 0.f, w3 = 0.f;
      if (idx < end) {
        s = ssrc[idx];
        float4 ev = *(const float4*)(esj + (size_t)s * 4);
        w0 = __expf(leaky(ev.x + edv.x));
        w1 = __expf(leaky(ev.y + edv.y));
        w2 = __expf(leaky(ev.z + edv.z));
        w3 = __expf(leaky(ev.w + edv.w));
      }
      int n_e = min(64, end - base);
      #pragma unroll 2
      for (int i = 0; i < n_e; i++) {
        int si   = __shfl(s, i);
        float b0 = __shfl(w0, i), b1 = __shfl(w1, i),
              b2 = __shfl(w2, i), b3 = __shfl(w3, i);
        float wh = sel4(b0, b1, b2, b3, h);
        u16x4 f = *(const u16x4*)(hfj + (size_t)si * 256 + lane * 4);
        acc[j][0] += wh * bf2f(f[0]);
        acc[j][1] += wh * bf2f(f[1]);
        acc[j][2] += wh * bf2f(f[2]);
        acc[j][3] += wh * bf2f(f[3]);
        den[j] += wh;
      }
    }
  }

  float4* xp = (float4*)(x0 + (size_t)node * 256 + lane * 4);
  float4 cur = *xp;
  #pragma unroll
  for (int j = 0; j < 4; j++) {
    if (den[j] > 0.f) {
      float inv = 1.f / den[j];
      cur.x += acc[j][0] * inv;
      cur.y += acc[j][1] * inv;
      cur.z += acc[j][2] * inv;
      cur.w += acc[j][3] * inv;
    }
  }
  *xp = cur;
}

// ---------------- layer 2 fused: 5 skinny GEMMs + scores ----------------
__global__ __launch_bounds__(256) void layer2_fused_k(
    const unsigned short* __restrict__ xa,  // [NN][256] bf16
    const float* __restrict__ skW,          // [256][2]
    const float* __restrict__ W,            // [4][256][2]
    const float* __restrict__ As2,          // [4][2]
    const float* __restrict__ Ad2,          // [4][2]
    const float* __restrict__ skbe,         // [2]
    float* __restrict__ x02,                // [NN][2]
    float* __restrict__ hf2,                // [4][NN][2]
    float* __restrict__ es2,                // [4][NN]
    float* __restrict__ ed2) {              // [4][NN]
  __shared__ float wsk[256][2];
  __shared__ float wcl[4][256][2];
  int t = threadIdx.x;
  wsk[t][0] = skW[t * 2];
  wsk[t][1] = skW[t * 2 + 1];
  #pragma unroll
  for (int j = 0; j < 4; j++) {
    wcl[j][t][0] = W[j * 512 + t * 2];
    wcl[j][t][1] = W[j * 512 + t * 2 + 1];
  }
  __syncthreads();
  int node = blockIdx.x * 256 + t;
  if (node >= NN) return;
  const unsigned short* row = xa + (size_t)node * 256;
  float s0 = 0.f, s1 = 0.f;
  float h[4][2] = {};
  for (int k = 0; k < 256; k += 4) {
    u16x4 xr = *(const u16x4*)(row + k);
    #pragma unroll
    for (int q = 0; q < 4; q++) {
      float xv = bf2f(xr[q]);
      s0 += xv * wsk[k + q][0];
      s1 += xv * wsk[k + q][1];
      #pragma unroll
      for (int j = 0; j < 4; j++) {
        h[j][0] += xv * wcl[j][k + q][0];
        h[j][1] += xv * wcl[j][k + q][1];
      }
    }
  }
  x02[(size_t)node * 2]     = s0 + skbe[0];
  x02[(size_t)node * 2 + 1] = s1 + skbe[1];
  #pragma unroll
  for (int j = 0; j < 4; j++) {
    hf2[((size_t)j * NN + node) * 2]     = h[j][0];
    hf2[((size_t)j * NN + node) * 2 + 1] = h[j][1];
    es2[(size_t)j * NN + node] = h[j][0] * As2[j * 2] + h[j][1] * As2[j * 2 + 1];
    ed2[(size_t)j * NN + node] = h[j][0] * Ad2[j * 2] + h[j][1] * Ad2[j * 2 + 1];
  }
}

// ---------------- fused aggregate for layer 2 (H=1, D=2) ----------------
__global__ __launch_bounds__(256) void gat_agg2_fused_k(
    const float* __restrict__ hf2,  // [4][NN][2]
    const float* __restrict__ es2,  // [4][NN]
    const float* __restrict__ ed2,  // [4][NN]
    const int* __restrict__ rs, const int* __restrict__ ssrc,
    float* __restrict__ x0) {       // [NN][2]
  int node = blockIdx.x * 4 + (threadIdx.x >> 6);
  int lane = threadIdx.x & 63;
  if (node >= NN) return;
  float add0 = 0.f, add1 = 0.f;
  #pragma unroll
  for (int j = 0; j < 4; j++) {
    int beg = rs[node * 4 + j], end = rs[node * 4 + j + 1];
    if (beg == end) continue;
    float edv = ed2[(size_t)j * NN + node];
    float nw = 0.f, n0 = 0.f, n1 = 0.f;
    for (int idx = beg + lane; idx < end; idx += 64) {
      int s = ssrc[idx];
      float w = __expf(leaky(es2[(size_t)j * NN + s] + edv));
      float2 f = *(const float2*)(hf2 + ((size_t)j * NN + s) * 2);
      nw += w; n0 += w * f.x; n1 += w * f.y;
    }
    #pragma unroll
    for (int off = 32; off > 0; off >>= 1) {
      nw += __shfl_xor(nw, off);
      n0 += __shfl_xor(n0, off);
      n1 += __shfl_xor(n1, off);
    }
    float inv = 1.f / nw;
    add0 += n0 * inv;
    add1 += n1 * inv;
  }
  if (lane == 0) {
    x0[(size_t)node * 2]     += add0;
    x0[(size_t)node * 2 + 1] += add1;
  }
}

__global__ void relu_k(const float* __restrict__ in, float* __restrict__ out, int n) {
  for (int i = blockIdx.x * 256 + threadIdx.x; i < n; i += gridDim.x * 256)
    out[i] = fmaxf(in[i], 0.f);
}

// ---------------- launch ----------------
extern "C" void kernel_launch(void* const* d_in, const int* in_sizes, int n_in,
                              void* d_out, int out_size, void* d_ws, size_t ws_size,
                              hipStream_t stream) {
  (void)in_sizes; (void)n_in; (void)out_size; (void)ws_size;
  const float* x_in = (const float*)d_in[0];
  const int* ei  = (const int*)d_in[1];
  const int* cls = (const int*)d_in[2];
  const float *W[3], *Asr[3], *Adr[3], *cb[3], *skW[3], *skb[3], *bng[3], *bnb[3];
  for (int i = 0; i < 3; i++) {
    int b = 3 + 8 * i;
    W[i]   = (const float*)d_in[b + 0];
    Asr[i] = (const float*)d_in[b + 1];
    Adr[i] = (const float*)d_in[b + 2];
    cb[i]  = (const float*)d_in[b + 3];
    skW[i] = (const float*)d_in[b + 4];
    skb[i] = (const float*)d_in[b + 5];
    bng[i] = (const float*)d_in[b + 6];
    bnb[i] = (const float*)d_in[b + 7];
  }
  float* out = (float*)d_out;

  char* wsp = (char*)d_ws;
  auto alloc = [&](size_t bytes) {
    char* p = wsp;
    wsp += (bytes + 255) & ~(size_t)255;
    return p;
  };
  float*          x0     = (float*)alloc((size_t)NN * 256 * 4);
  unsigned short* xa     = (unsigned short*)alloc((size_t)NN * 256 * 2);
  unsigned short* hfeat4 = (unsigned short*)alloc((size_t)4 * NN * 256 * 2);
  float*          hf2    = (float*)alloc((size_t)4 * NN * 2 * 4);
  float*          es4    = (float*)alloc((size_t)4 * NN * 4 * 4);
  float*          ed4    = (float*)alloc((size_t)4 * NN * 4 * 4);
  float*          stats  = (float*)alloc(512 * 4);
  float*          scale  = (float*)alloc(256 * 4);
  float*          shift  = (float*)alloc(256 * 4);
  float*          skbe   = (float*)alloc(256 * 4);
  unsigned short* wt     = (unsigned short*)alloc((size_t)409600 * 2);
  int*            counts = (int*)alloc((size_t)NN * 4 * 4);
  int*            rs     = (int*)alloc(((size_t)NN * 4 + 1) * 4);
  int*            cursor = (int*)alloc((size_t)NN * 4 * 4);
  int*            bsum   = (int*)alloc(256 * 4);
  int*            ssrc   = (int*)alloc((size_t)EE * 4);

  // ---- CSR by (dst, class) ----
  hipMemsetAsync(counts, 0, (size_t)NN * 4 * 4, stream);
  hipMemsetAsync(cursor, 0, (size_t)NN * 4 * 4, stream);
  count_edges_k<<<(EE + 255) / 256, 256, 0, stream>>>(ei, cls, counts);
  scan_local_k<<<196, 256, 0, stream>>>(counts, rs, bsum, NN * 4);
  scan_bsum_k<<<1, 256, 0, stream>>>(bsum, 196);
  scan_add_k<<<196, 256, 0, stream>>>(rs, bsum, NN * 4);
  fill_edges_k<<<(EE + 255) / 256, 256, 0, stream>>>(ei, cls, rs, cursor, ssrc);

  // ---- weights -> bf16 transposed (layers 0/1) ----
  conv_weights_k<<<1600, 256, 0, stream>>>(skW[0], W[0], skW[1], W[1], wt);

  // ---- layers 0 and 1 ----
  for (int L = 0; L < 2; L++) {
    int din = (L == 0) ? 64 : 256;
    int total4 = NN * din / 4;
    const float* lin = (L == 0) ? x_in : x0;
    hipMemsetAsync(stats, 0, 512 * 4, stream);
    if (L == 0) {
      bn_stats_k<false><<<512, 256, 0, stream>>>(lin, stats, din, total4);
    } else {
      bn_stats_k<true><<<512, 256, 0, stream>>>(lin, stats, din, total4);
    }
    bn_finalize_k<<<1, 256, 0, stream>>>(stats, bng[L], bnb[L], scale, shift, din,
                                         skb[L], cb[L], skbe, 256);
    if (L == 0) {
      bn_apply_bf16_k<false><<<1024, 256, 0, stream>>>(lin, xa, scale, shift, din - 1, total4);
    } else {
      bn_apply_bf16_k<true><<<1024, 256, 0, stream>>>(lin, xa, scale, shift, din - 1, total4);
    }

    const unsigned short* wsk = wt + (L ? 81920 : 0);
    dim3 ggs(2, (NN + 127) / 128, 1);
    gemm_bf16_k<<<ggs, 256, 0, stream>>>(xa, wsk, skbe, x0, nullptr,
                                         nullptr, nullptr, nullptr, nullptr,
                                         NN, din, 256, 0, 0);
    const unsigned short* wcv = wt + (L ? 147456 : 16384);
    int sB = L ? 65536 : 16384;
    dim3 ggc(2, (NN + 127) / 128, 4);
    gemm_bf16_k<<<ggc, 256, 0, stream>>>(xa, wcv, nullptr, nullptr, hfeat4,
                                         Asr[L], Adr[L], es4, ed4,
                                         NN, din, 256, sB, (long long)NN * 256);
    gat_agg4_fused_k<<<(NN + 3) / 4, 256, 0, stream>>>(hfeat4, es4, ed4, rs, ssrc, x0);
  }

  // ---- layer 2 ----
  hipMemsetAsync(stats, 0, 512 * 4, stream);
  bn_stats_k<true><<<512, 256, 0, stream>>>(x0, stats, 256, NN * 64);
  bn_finalize_k<<<1, 256, 0, stream>>>(stats, bng[2], bnb[2], scale, shift, 256,
                                       skb[2], cb[2], skbe, 2);
  bn_apply_bf16_k<true><<<1024, 256, 0, stream>>>(x0, xa, scale, shift, 255, NN * 64);
  layer2_fused_k<<<(NN + 255) / 256, 256, 0, stream>>>(xa, skW[2], W[2], Asr[2], Adr[2],
                                                       skbe, x0, hf2, es4, ed4);
  gat_agg2_fused_k<<<(NN + 3) / 4, 256, 0, stream>>>(hf2, es4, ed4, rs, ssrc, x0);
  relu_k<<<64, 256, 0, stream>>>(x0, out, NN * 2);
}

// Round 6
// 692.162 us; speedup vs baseline: 1.4213x; 1.0964x over previous
//
#include <hip/hip_runtime.h>
#include <cstddef>
#include <cstdint>

#define NN 50000
#define EE 800000

constexpr float BN_EPS   = 1e-5f;
constexpr float NEGSLOPE = 0.2f;

typedef short s16x8 __attribute__((ext_vector_type(8)));
typedef float f32x4 __attribute__((ext_vector_type(4)));
typedef unsigned short u16x4 __attribute__((ext_vector_type(4)));

__device__ __forceinline__ unsigned short f2bf(float f) {
  unsigned int u = __float_as_uint(f);
  unsigned int r = (u + 0x7fffu + ((u >> 16) & 1u)) >> 16;
  return (unsigned short)r;
}
__device__ __forceinline__ float bf2f(unsigned short u) {
  return __uint_as_float(((unsigned int)u) << 16);
}
__device__ __forceinline__ float leaky(float e) { return e >= 0.f ? e : NEGSLOPE * e; }
__device__ __forceinline__ float sel4(float v0, float v1, float v2, float v3, int h) {
  float r = v0;
  r = (h == 1) ? v1 : r;
  r = (h == 2) ? v2 : r;
  r = (h == 3) ? v3 : r;
  return r;
}
__device__ __forceinline__ void gl_lds16(const unsigned short* g, unsigned short* l) {
  __builtin_amdgcn_global_load_lds(
      (const __attribute__((address_space(1))) unsigned int*)(g),
      (__attribute__((address_space(3))) unsigned int*)(l), 16, 0, 0);
}

// ---------------- CSR build: group edges by (dst*4 + class) ----------------
__global__ void count_edges_k(const int* __restrict__ ei, const int* __restrict__ cls,
                              int* __restrict__ counts) {
  int e = blockIdx.x * 256 + threadIdx.x;
  if (e >= EE) return;
  int dst = ei[EE + e];
  int c   = cls[e];
  atomicAdd(&counts[dst * 4 + c], 1);
}

__global__ void scan_local_k(const int* __restrict__ counts, int* __restrict__ rs,
                             int* __restrict__ bsum, int n) {
  __shared__ int sh[256];
  int b = blockIdx.x, t = threadIdx.x;
  int base = b * 1024;
  int v[4];
  #pragma unroll
  for (int q = 0; q < 4; q++) {
    int i = base + t * 4 + q;
    v[q] = (i < n) ? counts[i] : 0;
  }
  v[1] += v[0]; v[2] += v[1]; v[3] += v[2];
  sh[t] = v[3];
  __syncthreads();
  for (int off = 1; off < 256; off <<= 1) {
    int x = (t >= off) ? sh[t - off] : 0;
    __syncthreads();
    sh[t] += x;
    __syncthreads();
  }
  int prev = (t > 0) ? sh[t - 1] : 0;
  #pragma unroll
  for (int q = 0; q < 4; q++) {
    int i = base + t * 4 + q;
    if (i < n) rs[i + 1] = prev + v[q];
  }
  if (t == 255) bsum[b] = sh[255];
}

__global__ void scan_bsum_k(int* __restrict__ bsum, int nb) {
  __shared__ int sh[256];
  int t = threadIdx.x;
  sh[t] = (t < nb) ? bsum[t] : 0;
  __syncthreads();
  for (int off = 1; off < 256; off <<= 1) {
    int x = (t >= off) ? sh[t - off] : 0;
    __syncthreads();
    sh[t] += x;
    __syncthreads();
  }
  if (t < nb) bsum[t] = (t > 0) ? sh[t - 1] : 0;
}

__global__ void scan_add_k(int* __restrict__ rs, const int* __restrict__ bsum, int n) {
  int b = blockIdx.x, t = threadIdx.x;
  int off = bsum[b];
  #pragma unroll
  for (int q = 0; q < 4; q++) {
    int i = b * 1024 + t * 4 + q;
    if (i < n) rs[i + 1] += off;
  }
  if (b == 0 && t == 0) rs[0] = 0;
}

__global__ void fill_edges_k(const int* __restrict__ ei, const int* __restrict__ cls,
                             const int* __restrict__ rs, int* __restrict__ cursor,
                             int* __restrict__ ssrc) {
  int e = blockIdx.x * 256 + threadIdx.x;
  if (e >= EE) return;
  int dst = ei[EE + e];
  int c   = cls[e];
  int bin = dst * 4 + c;
  int pos = rs[bin] + atomicAdd(&cursor[bin], 1);
  ssrc[pos] = ei[e];
}

// ---------------- BatchNorm (float4 loads, register accumulation) ----------
template <bool RELU>
__global__ void bn_stats_k(const float* __restrict__ x, float* __restrict__ sums,
                           int din, int total4) {
  __shared__ float ls[512];
  int t = threadIdx.x;
  for (int i = t; i < 2 * din; i += 256) ls[i] = 0.f;
  __syncthreads();
  int dmask = din - 1;
  int start = blockIdx.x * 256 + t;
  int c0 = (start * 4) & dmask;
  float s[4] = {0.f, 0.f, 0.f, 0.f};
  float ss[4] = {0.f, 0.f, 0.f, 0.f};
  for (int idx = start; idx < total4; idx += gridDim.x * 256) {
    float4 v = ((const float4*)x)[idx];
    float a0 = RELU ? fmaxf(v.x, 0.f) : v.x;
    float a1 = RELU ? fmaxf(v.y, 0.f) : v.y;
    float a2 = RELU ? fmaxf(v.z, 0.f) : v.z;
    float a3 = RELU ? fmaxf(v.w, 0.f) : v.w;
    s[0] += a0; s[1] += a1; s[2] += a2; s[3] += a3;
    ss[0] += a0 * a0; ss[1] += a1 * a1; ss[2] += a2 * a2; ss[3] += a3 * a3;
  }
  #pragma unroll
  for (int q = 0; q < 4; q++) {
    atomicAdd(&ls[c0 + q], s[q]);
    atomicAdd(&ls[din + c0 + q], ss[q]);
  }
  __syncthreads();
  for (int i = t; i < 2 * din; i += 256) atomicAdd(&sums[i], ls[i]);
}

__global__ void bn_finalize_k(const float* __restrict__ sums, const float* __restrict__ g,
                              const float* __restrict__ b, float* __restrict__ scale,
                              float* __restrict__ shift, int din,
                              const float* __restrict__ skb, const float* __restrict__ cb,
                              float* __restrict__ skbe, int hd) {
  int i = threadIdx.x;
  if (i < din) {
    float m  = sums[i] / (float)NN;
    float v  = sums[din + i] / (float)NN - m * m;
    float r  = rsqrtf(v + BN_EPS);
    float sc = r * g[i];
    scale[i] = sc;
    shift[i] = b[i] - m * sc;
  }
  if (i < hd) {
    float acc = skb[i];
    #pragma unroll
    for (int j = 0; j < 4; j++) acc += cb[j * hd + i];
    skbe[i] = acc;
  }
}

template <bool RELU>
__global__ void bn_apply_bf16_k(const float* __restrict__ x, unsigned short* __restrict__ xn,
                                const float* __restrict__ scale, const float* __restrict__ shift,
                                int dmask, int total4) {
  for (int i = blockIdx.x * 256 + threadIdx.x; i < total4; i += gridDim.x * 256) {
    float4 v = ((const float4*)x)[i];
    int c0 = (i * 4) & dmask;
    if (RELU) {
      v.x = fmaxf(v.x, 0.f); v.y = fmaxf(v.y, 0.f);
      v.z = fmaxf(v.z, 0.f); v.w = fmaxf(v.w, 0.f);
    }
    u16x4 o;
    o[0] = f2bf(v.x * scale[c0 + 0] + shift[c0 + 0]);
    o[1] = f2bf(v.y * scale[c0 + 1] + shift[c0 + 1]);
    o[2] = f2bf(v.z * scale[c0 + 2] + shift[c0 + 2]);
    o[3] = f2bf(v.w * scale[c0 + 3] + shift[c0 + 3]);
    ((u16x4*)xn)[i] = o;
  }
}

// ---------------- weight convert+transpose to bf16 (layers 0/1) ----------------
__global__ void conv_weights_k(const float* __restrict__ skW0, const float* __restrict__ W0,
                               const float* __restrict__ skW1, const float* __restrict__ W1,
                               unsigned short* __restrict__ wt) {
  int o = blockIdx.x * 256 + threadIdx.x;
  if (o >= 409600) return;
  float v;
  if (o < 16384) {                       // skW0^T [256][64]
    int n = o >> 6, k = o & 63;
    v = skW0[k * 256 + n];
  } else if (o < 81920) {                // W0^T [4][256][64]
    int w = o - 16384; int j = w >> 14; w &= 16383;
    int n = w >> 6, k = w & 63;
    v = W0[j * 16384 + k * 256 + n];
  } else if (o < 147456) {               // skW1^T [256][256]
    int w = o - 81920;
    int n = w >> 8, k = w & 255;
    v = skW1[k * 256 + n];
  } else {                               // W1^T [4][256][256]
    int w = o - 147456; int j = w >> 16; w &= 65535;
    int n = w >> 8, k = w & 255;
    v = W1[j * 65536 + k * 256 + n];
  }
  wt[o] = f2bf(v);
}

// ---------------- bf16 MFMA GEMM: z=0 -> skip (f32+bias), z=1..4 -> conv ----
__global__ __launch_bounds__(256) void gemm_bf16_k(
    const unsigned short* __restrict__ A,    // [M,K] bf16
    const unsigned short* __restrict__ BtSk, // [256,K] skip weights
    const unsigned short* __restrict__ BtCv, // [4][256,K] conv weights
    const float* __restrict__ skbe,          // [256] bias for skip
    float* __restrict__ x0,                  // f32 skip out
    unsigned short* __restrict__ hfeat4,     // [4][NN][256] bf16 conv out
    const float* __restrict__ asrc,          // [4][256]
    const float* __restrict__ adst,          // [4][256]
    float* __restrict__ es4,                 // [4][NN][4]
    float* __restrict__ ed4,                 // [4][NN][4]
    int M, int K) {
  __shared__ unsigned short As[128 * 32];
  __shared__ unsigned short Bs[128 * 32];
  int z = blockIdx.z;
  const unsigned short* Bt = (z == 0) ? BtSk : BtCv + (size_t)(z - 1) * 256 * K;
  int tid  = threadIdx.x;
  int lane = tid & 63;
  int w    = tid >> 6;
  int lm = lane & 15, lq = lane >> 4;
  int row0 = blockIdx.y * 128, col0 = blockIdx.x * 128;
  int wr = (w >> 1) * 64, wc = (w & 1) * 64;
  f32x4 acc[4][4];
  #pragma unroll
  for (int i = 0; i < 4; i++)
    #pragma unroll
    for (int j = 0; j < 4; j++) acc[i][j] = {0.f, 0.f, 0.f, 0.f};
  int ldsbase = (tid & ~63) * 16;

  for (int k0 = 0; k0 < K; k0 += 32) {
    #pragma unroll
    for (int r = 0; r < 2; r++) {
      int ia = r * 256 + tid;
      int arow = row0 + (ia >> 2);
      if (arow >= M) arow = M - 1;
      const unsigned short* ga = A + (size_t)arow * K + k0 + (ia & 3) * 8;
      gl_lds16(ga, (unsigned short*)((char*)As + r * 4096 + ldsbase));
      int bcol = col0 + (ia >> 2);
      const unsigned short* gb = Bt + (size_t)bcol * K + k0 + (ia & 3) * 8;
      gl_lds16(gb, (unsigned short*)((char*)Bs + r * 4096 + ldsbase));
    }
    __syncthreads();
    s16x8 af[4], bfr[4];
    #pragma unroll
    for (int i = 0; i < 4; i++)
      af[i] = *(const s16x8*)&As[(wr + i * 16 + lm) * 32 + lq * 8];
    #pragma unroll
    for (int j = 0; j < 4; j++)
      bfr[j] = *(const s16x8*)&Bs[(wc + j * 16 + lm) * 32 + lq * 8];
    #pragma unroll
    for (int i = 0; i < 4; i++)
      #pragma unroll
      for (int j = 0; j < 4; j++)
        acc[i][j] = __builtin_amdgcn_mfma_f32_16x16x32_bf16(af[i], bfr[j], acc[i][j], 0, 0, 0);
    __syncthreads();
  }

  if (z == 0) {
    #pragma unroll
    for (int i = 0; i < 4; i++)
      #pragma unroll
      for (int j = 0; j < 4; j++) {
        int c = col0 + wc + j * 16 + lm;
        #pragma unroll
        for (int rg = 0; rg < 4; rg++) {
          int r = row0 + wr + i * 16 + lq * 4 + rg;
          if (r < M) x0[(size_t)r * 256 + c] = acc[i][j][rg] + skbe[c];
        }
      }
  } else {
    int cl = z - 1;
    unsigned short* Cb = hfeat4 + (size_t)cl * NN * 256;
    #pragma unroll
    for (int i = 0; i < 4; i++)
      #pragma unroll
      for (int j = 0; j < 4; j++) {
        int c = col0 + wc + j * 16 + lm;
        #pragma unroll
        for (int rg = 0; rg < 4; rg++) {
          int r = row0 + wr + i * 16 + lq * 4 + rg;
          if (r < M) Cb[(size_t)r * 256 + c] = f2bf(acc[i][j][rg]);
        }
      }
    // fused attention scores: each wave's 64-col span == one head
    int hh = (col0 + wc) >> 6;
    float as_v[4], ad_v[4];
    #pragma unroll
    for (int j = 0; j < 4; j++) {
      int gcol = col0 + wc + j * 16 + lm;
      as_v[j] = asrc[cl * 256 + gcol];
      ad_v[j] = adst[cl * 256 + gcol];
    }
    #pragma unroll
    for (int i = 0; i < 4; i++) {
      #pragma unroll
      for (int rg = 0; rg < 4; rg++) {
        float se = 0.f, sd = 0.f;
        #pragma unroll
        for (int j = 0; j < 4; j++) {
          se += acc[i][j][rg] * as_v[j];
          sd += acc[i][j][rg] * ad_v[j];
        }
        #pragma unroll
        for (int off = 8; off > 0; off >>= 1) {
          se += __shfl_xor(se, off);
          sd += __shfl_xor(sd, off);
        }
        int r = row0 + wr + i * 16 + lq * 4 + rg;
        if (r < M) {
          if (lm == 0) es4[((size_t)cl * NN + r) * 4 + hh] = se;
          if (lm == 1) ed4[((size_t)cl * NN + r) * 4 + hh] = sd;
        }
      }
    }
  }
}

// ---------------- fused aggregate: whole node in one 64-edge batch ----------
// lane = edge slot (all 4 classes, sorted by class); per-class softmax dens
// via 64-lane prefix scan; alpha normalized upfront -> single accumulator.
__global__ __launch_bounds__(256) void gat_agg4_fused_k(
    const unsigned short* __restrict__ hfeat4,  // [4][NN][256] bf16
    const float* __restrict__ es4,              // [4][NN][4]
    const float* __restrict__ ed4,              // [4][NN][4]
    const int* __restrict__ rs, const int* __restrict__ ssrc,
    float* __restrict__ x0) {                   // [NN][256] += msg
  __shared__ float aw[4][256];  // per-wave alpha[e][h]
  int wv   = threadIdx.x >> 6;
  int node = blockIdx.x * 4 + wv;
  int lane = threadIdx.x & 63;
  if (node >= NN) return;
  int r0 = rs[node * 4 + 0], r1 = rs[node * 4 + 1], r2 = rs[node * 4 + 2],
      r3 = rs[node * 4 + 3], r4 = rs[node * 4 + 4];
  int En = r4 - r0;
  if (En == 0) return;
  int hd = lane >> 4;  // head for feature phase (cols lane*4..+3)
  float acc0 = 0.f, acc1 = 0.f, acc2 = 0.f, acc3 = 0.f;

  if (En <= 64) {
    // ---- fast path: one batch covers every class of this node ----
    int idx = r0 + lane;
    bool valid = idx < r4;
    int j = 0, ri = 0;
    float w0 = 0.f, w1 = 0.f, w2 = 0.f, w3 = 0.f;
    if (valid) {
      j = (idx >= r1) + (idx >= r2) + (idx >= r3);
      int s = ssrc[idx];
      ri = j * NN + s;
      float4 ev = *(const float4*)(es4 + (size_t)ri * 4);
      float4 dv = *(const float4*)(ed4 + ((size_t)j * NN + node) * 4);
      w0 = __expf(leaky(ev.x + dv.x));
      w1 = __expf(leaky(ev.y + dv.y));
      w2 = __expf(leaky(ev.z + dv.z));
      w3 = __expf(leaky(ev.w + dv.w));
    }
    // inclusive prefix scan over 64 lanes (classes are contiguous)
    float p0 = w0, p1 = w1, p2 = w2, p3 = w3;
    #pragma unroll
    for (int off = 1; off < 64; off <<= 1) {
      float t0 = __shfl_up(p0, off), t1 = __shfl_up(p1, off);
      float t2 = __shfl_up(p2, off), t3 = __shfl_up(p3, off);
      if (lane >= off) { p0 += t0; p1 += t1; p2 += t2; p3 += t3; }
    }
    if (valid) {
      int b1 = r1 - r0, b2 = r2 - r0, b3 = r3 - r0, b4 = r4 - r0;
      int endl = sel4((float)b1, (float)b2, (float)b3, (float)b4, j);
      int begl = sel4(0.f, (float)b1, (float)b2, (float)b3, j);
      int ei2 = (int)endl - 1;
      int bi2 = (int)begl - 1;
      float d0 = __shfl(p0, ei2), d1 = __shfl(p1, ei2);
      float d2 = __shfl(p2, ei2), d3 = __shfl(p3, ei2);
      float q0 = __shfl(p0, bi2 < 0 ? 0 : bi2), q1 = __shfl(p1, bi2 < 0 ? 0 : bi2);
      float q2 = __shfl(p2, bi2 < 0 ? 0 : bi2), q3 = __shfl(p3, bi2 < 0 ? 0 : bi2);
      if (bi2 < 0) { q0 = 0.f; q1 = 0.f; q2 = 0.f; q3 = 0.f; }
      w0 /= (d0 - q0); w1 /= (d1 - q1); w2 /= (d2 - q2); w3 /= (d3 - q3);
    } else {
      w0 = w1 = w2 = w3 = 0.f;
    }
    *(float4*)&aw[wv][lane * 4] = make_float4(w0, w1, w2, w3);
    __builtin_amdgcn_s_waitcnt(0);  // lgkmcnt(0): LDS writes visible in-wave
    #pragma unroll 2
    for (int i = 0; i < En; i++) {
      int rib = __shfl(ri, i);
      float a = aw[wv][i * 4 + hd];
      u16x4 f = *(const u16x4*)(hfeat4 + ((size_t)rib << 8) + lane * 4);
      acc0 += a * bf2f(f[0]);
      acc1 += a * bf2f(f[1]);
      acc2 += a * bf2f(f[2]);
      acc3 += a * bf2f(f[3]);
    }
  } else {
    // ---- general path (rare: En > 64): per-class, unnormalized + divide ----
    #pragma unroll
    for (int j = 0; j < 4; j++) {
      int beg = (j == 0) ? r0 : (j == 1) ? r1 : (j == 2) ? r2 : r3;
      int end = (j == 0) ? r1 : (j == 1) ? r2 : (j == 2) ? r3 : r4;
      if (beg == end) continue;
      float4 edv = *(const float4*)(ed4 + ((size_t)j * NN + node) * 4);
      const float* esj = es4 + (size_t)j * NN * 4;
      const unsigned short* hfj = hfeat4 + (size_t)j * NN * 256;
      float n0 = 0.f, n1 = 0.f, n2 = 0.f, n3 = 0.f, den = 0.f;
      for (int b2 = beg; b2 < end; b2 += 64) {
        int idx = b2 + lane;
        int s = 0;
        float w0 = 0.f, w1 = 0.f, w2 = 0.f, w3 = 0.f;
        if (idx < end) {
          s = ssrc[idx];
          float4 ev = *(const float4*)(esj + (size_t)s * 4);
          w0 = __expf(leaky(ev.x + edv.x));
          w1 = __expf(leaky(ev.y + edv.y));
          w2 = __expf(leaky(ev.z + edv.z));
          w3 = __expf(leaky(ev.w + edv.w));
        }
        int n_e = min(64, end - b2);
        for (int i = 0; i < n_e; i++) {
          int si = __shfl(s, i);
          float c0 = __shfl(w0, i), c1 = __shfl(w1, i),
                c2 = __shfl(w2, i), c3 = __shfl(w3, i);
          float wh = sel4(c0, c1, c2, c3, hd);
          u16x4 f = *(const u16x4*)(hfj + (size_t)si * 256 + lane * 4);
          n0 += wh * bf2f(f[0]);
          n1 += wh * bf2f(f[1]);
          n2 += wh * bf2f(f[2]);
          n3 += wh * bf2f(f[3]);
          den += wh;
        }
      }
      float inv = 1.f / den;
      acc0 += n0 * inv; acc1 += n1 * inv; acc2 += n2 * inv; acc3 += n3 * inv;
    }
  }

  float4* xp = (float4*)(x0 + (size_t)node * 256 + lane * 4);
  float4 cur = *xp;
  cur.x += acc0; cur.y += acc1; cur.z += acc2; cur.w += acc3;
  *xp = cur;
}

// ---------------- layer 2 fused: 5 skinny GEMMs + scores ----------------
__global__ __launch_bounds__(256) void layer2_fused_k(
    const unsigned short* __restrict__ xa,  // [NN][256] bf16
    const float* __restrict__ skW,          // [256][2]
    const float* __restrict__ W,            // [4][256][2]
    const float* __restrict__ As2,          // [4][2]
    const float* __restrict__ Ad2,          // [4][2]
    const float* __restrict__ skbe,         // [2]
    float* __restrict__ x02,                // [NN][2]
    float* __restrict__ hf2,                // [4][NN][2]
    float* __restrict__ es2,                // [4][NN]
    float* __restrict__ ed2) {              // [4][NN]
  __shared__ float wsk[256][2];
  __shared__ float wcl[4][256][2];
  int t = threadIdx.x;
  wsk[t][0] = skW[t * 2];
  wsk[t][1] = skW[t * 2 + 1];
  #pragma unroll
  for (int j = 0; j < 4; j++) {
    wcl[j][t][0] = W[j * 512 + t * 2];
    wcl[j][t][1] = W[j * 512 + t * 2 + 1];
  }
  __syncthreads();
  int node = blockIdx.x * 256 + t;
  if (node >= NN) return;
  const unsigned short* row = xa + (size_t)node * 256;
  float s0 = 0.f, s1 = 0.f;
  float h[4][2] = {};
  for (int k = 0; k < 256; k += 4) {
    u16x4 xr = *(const u16x4*)(row + k);
    #pragma unroll
    for (int q = 0; q < 4; q++) {
      float xv = bf2f(xr[q]);
      s0 += xv * wsk[k + q][0];
      s1 += xv * wsk[k + q][1];
      #pragma unroll
      for (int j = 0; j < 4; j++) {
        h[j][0] += xv * wcl[j][k + q][0];
        h[j][1] += xv * wcl[j][k + q][1];
      }
    }
  }
  x02[(size_t)node * 2]     = s0 + skbe[0];
  x02[(size_t)node * 2 + 1] = s1 + skbe[1];
  #pragma unroll
  for (int j = 0; j < 4; j++) {
    hf2[((size_t)j * NN + node) * 2]     = h[j][0];
    hf2[((size_t)j * NN + node) * 2 + 1] = h[j][1];
    es2[(size_t)j * NN + node] = h[j][0] * As2[j * 2] + h[j][1] * As2[j * 2 + 1];
    ed2[(size_t)j * NN + node] = h[j][0] * Ad2[j * 2] + h[j][1] * Ad2[j * 2 + 1];
  }
}

// ---------------- fused aggregate for layer 2 + final ReLU -> out ----------
__global__ __launch_bounds__(256) void gat_agg2_fused_k(
    const float* __restrict__ hf2,  // [4][NN][2]
    const float* __restrict__ es2,  // [4][NN]
    const float* __restrict__ ed2,  // [4][NN]
    const int* __restrict__ rs, const int* __restrict__ ssrc,
    const float* __restrict__ x02,  // [NN][2] skip values
    float* __restrict__ out) {      // [NN][2] = relu(skip + msgs)
  int node = blockIdx.x * 4 + (threadIdx.x >> 6);
  int lane = threadIdx.x & 63;
  if (node >= NN) return;
  float add0 = 0.f, add1 = 0.f;
  #pragma unroll
  for (int j = 0; j < 4; j++) {
    int beg = rs[node * 4 + j], end = rs[node * 4 + j + 1];
    if (beg == end) continue;
    float edv = ed2[(size_t)j * NN + node];
    float nw = 0.f, n0 = 0.f, n1 = 0.f;
    for (int idx = beg + lane; idx < end; idx += 64) {
      int s = ssrc[idx];
      float w = __expf(leaky(es2[(size_t)j * NN + s] + edv));
      float2 f = *(const float2*)(hf2 + ((size_t)j * NN + s) * 2);
      nw += w; n0 += w * f.x; n1 += w * f.y;
    }
    #pragma unroll
    for (int off = 32; off > 0; off >>= 1) {
      nw += __shfl_xor(nw, off);
      n0 += __shfl_xor(n0, off);
      n1 += __shfl_xor(n1, off);
    }
    float inv = 1.f / nw;
    add0 += n0 * inv;
    add1 += n1 * inv;
  }
  if (lane == 0) {
    out[(size_t)node * 2]     = fmaxf(x02[(size_t)node * 2] + add0, 0.f);
    out[(size_t)node * 2 + 1] = fmaxf(x02[(size_t)node * 2 + 1] + add1, 0.f);
  }
}

// ---------------- launch ----------------
extern "C" void kernel_launch(void* const* d_in, const int* in_sizes, int n_in,
                              void* d_out, int out_size, void* d_ws, size_t ws_size,
                              hipStream_t stream) {
  (void)in_sizes; (void)n_in; (void)out_size; (void)ws_size;
  const float* x_in = (const float*)d_in[0];
  const int* ei  = (const int*)d_in[1];
  const int* cls = (const int*)d_in[2];
  const float *W[3], *Asr[3], *Adr[3], *cb[3], *skW[3], *skb[3], *bng[3], *bnb[3];
  for (int i = 0; i < 3; i++) {
    int b = 3 + 8 * i;
    W[i]   = (const float*)d_in[b + 0];
    Asr[i] = (const float*)d_in[b + 1];
    Adr[i] = (const float*)d_in[b + 2];
    cb[i]  = (const float*)d_in[b + 3];
    skW[i] = (const float*)d_in[b + 4];
    skb[i] = (const float*)d_in[b + 5];
    bng[i] = (const float*)d_in[b + 6];
    bnb[i] = (const float*)d_in[b + 7];
  }
  float* out = (float*)d_out;

  char* wsp = (char*)d_ws;
  auto alloc = [&](size_t bytes) {
    char* p = wsp;
    wsp += (bytes + 255) & ~(size_t)255;
    return p;
  };
  float*          x0     = (float*)alloc((size_t)NN * 256 * 4);
  unsigned short* xa     = (unsigned short*)alloc((size_t)NN * 256 * 2);
  unsigned short* hfeat4 = (unsigned short*)alloc((size_t)4 * NN * 256 * 2);
  float*          hf2    = (float*)alloc((size_t)4 * NN * 2 * 4);
  float*          es4    = (float*)alloc((size_t)4 * NN * 4 * 4);
  float*          ed4    = (float*)alloc((size_t)4 * NN * 4 * 4);
  float*          x02    = (float*)alloc((size_t)NN * 2 * 4);
  float*          stats  = (float*)alloc(512 * 4);
  float*          scale  = (float*)alloc(256 * 4);
  float*          shift  = (float*)alloc(256 * 4);
  float*          skbe   = (float*)alloc(256 * 4);
  unsigned short* wt     = (unsigned short*)alloc((size_t)409600 * 2);
  int*            counts = (int*)alloc((size_t)NN * 4 * 4);
  int*            rs     = (int*)alloc(((size_t)NN * 4 + 1) * 4);
  int*            cursor = (int*)alloc((size_t)NN * 4 * 4);
  int*            bsum   = (int*)alloc(256 * 4);
  int*            ssrc   = (int*)alloc((size_t)EE * 4);

  // ---- CSR by (dst, class) ----
  hipMemsetAsync(counts, 0, (size_t)NN * 4 * 4, stream);
  hipMemsetAsync(cursor, 0, (size_t)NN * 4 * 4, stream);
  count_edges_k<<<(EE + 255) / 256, 256, 0, stream>>>(ei, cls, counts);
  scan_local_k<<<196, 256, 0, stream>>>(counts, rs, bsum, NN * 4);
  scan_bsum_k<<<1, 256, 0, stream>>>(bsum, 196);
  scan_add_k<<<196, 256, 0, stream>>>(rs, bsum, NN * 4);
  fill_edges_k<<<(EE + 255) / 256, 256, 0, stream>>>(ei, cls, rs, cursor, ssrc);

  // ---- weights -> bf16 transposed (layers 0/1) ----
  conv_weights_k<<<1600, 256, 0, stream>>>(skW[0], W[0], skW[1], W[1], wt);

  // ---- layers 0 and 1 ----
  for (int L = 0; L < 2; L++) {
    int din = (L == 0) ? 64 : 256;
    int total4 = NN * din / 4;
    const float* lin = (L == 0) ? x_in : x0;
    hipMemsetAsync(stats, 0, 512 * 4, stream);
    if (L == 0) {
      bn_stats_k<false><<<512, 256, 0, stream>>>(lin, stats, din, total4);
    } else {
      bn_stats_k<true><<<512, 256, 0, stream>>>(lin, stats, din, total4);
    }
    bn_finalize_k<<<1, 256, 0, stream>>>(stats, bng[L], bnb[L], scale, shift, din,
                                         skb[L], cb[L], skbe, 256);
    if (L == 0) {
      bn_apply_bf16_k<false><<<1024, 256, 0, stream>>>(lin, xa, scale, shift, din - 1, total4);
    } else {
      bn_apply_bf16_k<true><<<1024, 256, 0, stream>>>(lin, xa, scale, shift, din - 1, total4);
    }

    const unsigned short* wsk = wt + (L ? 81920 : 0);
    const unsigned short* wcv = wt + (L ? 147456 : 16384);
    dim3 gg(2, (NN + 127) / 128, 5);
    gemm_bf16_k<<<gg, 256, 0, stream>>>(xa, wsk, wcv, skbe, x0, hfeat4,
                                        Asr[L], Adr[L], es4, ed4, NN, din);
    gat_agg4_fused_k<<<(NN + 3) / 4, 256, 0, stream>>>(hfeat4, es4, ed4, rs, ssrc, x0);
  }

  // ---- layer 2 ----
  hipMemsetAsync(stats, 0, 512 * 4, stream);
  bn_stats_k<true><<<512, 256, 0, stream>>>(x0, stats, 256, NN * 64);
  bn_finalize_k<<<1, 256, 0, stream>>>(stats, bng[2], bnb[2], scale, shift, 256,
                                       skb[2], cb[2], skbe, 2);
  bn_apply_bf16_k<true><<<1024, 256, 0, stream>>>(x0, xa, scale, shift, 255, NN * 64);
  layer2_fused_k<<<(NN + 255) / 256, 256, 0, stream>>>(xa, skW[2], W[2], Asr[2], Adr[2],
                                                       skbe, x02, hf2, es4, ed4);
  gat_agg2_fused_k<<<(NN + 3) / 4, 256, 0, stream>>>(hf2, es4, ed4, rs, ssrc, x02, out);
}